// Round 6
// baseline (172.213 us; speedup 1.0000x reference)
//
#include <hip/hip_runtime.h>

// Problem: B=32, S=256, M=1024, N=32, O=32.
// out[b][s*32+o] = sum_k exp(-sum_n |proj[b,s,n,o]-proj[b,k,n,o]|),
// proj[b,s,j] = sum_m x[b,s,m] W[j,m],  j = n*32+o.

#define BS 8192      // B*S rows of x
#define MD 1024      // M
#define NO 1024      // N*O

typedef short short8 __attribute__((ext_vector_type(8)));    // 8 bf16 raw bits
typedef float f32x4 __attribute__((ext_vector_type(4)));
typedef _Float16 f16x2 __attribute__((ext_vector_type(2)));

template <typename T, typename F>
__device__ __forceinline__ T bc(F f) { return __builtin_bit_cast(T, f); }

// packed f16 ops pinned to the VOP3P instructions
__device__ __forceinline__ unsigned pk_max(unsigned a, unsigned b) {
  unsigned d;
  asm("v_pk_max_f16 %0, %1, %2" : "=v"(d) : "v"(a), "v"(b));
  return d;
}
__device__ __forceinline__ unsigned pk_add(unsigned a, unsigned b) {
  unsigned d;
  asm("v_pk_add_f16 %0, %1, %2" : "=v"(d) : "v"(a), "v"(b));
  return d;
}

// ---------------- cast f32 -> bf16 (RNE), 4 elems/thread ----------------
__global__ __launch_bounds__(256) void cast_bf16_kernel(const float* __restrict__ in,
                                                        unsigned short* __restrict__ out,
                                                        int n4) {
  int i = blockIdx.x * 256 + threadIdx.x;
  if (i >= n4) return;
  float4 v = reinterpret_cast<const float4*>(in)[i];
  ushort4 u;
  unsigned b;
  b = __float_as_uint(v.x); u.x = (unsigned short)((b + 0x7FFFu + ((b >> 16) & 1u)) >> 16);
  b = __float_as_uint(v.y); u.y = (unsigned short)((b + 0x7FFFu + ((b >> 16) & 1u)) >> 16);
  b = __float_as_uint(v.z); u.z = (unsigned short)((b + 0x7FFFu + ((b >> 16) & 1u)) >> 16);
  b = __float_as_uint(v.w); u.w = (unsigned short)((b + 0x7FFFu + ((b >> 16) & 1u)) >> 16);
  reinterpret_cast<ushort4*>(out)[i] = u;
}

// ---------------- GEMM: projT[j][i] = sum_k W[j,k] x[i,k], emitted as
// projP[m][o][i] = packed f16x2 (proj[n=2m], proj[n=2m+1]) for column o ----
__global__ __launch_bounds__(256) void gemm_kernel(const unsigned short* __restrict__ xb,
                                                   const unsigned short* __restrict__ wb,
                                                   unsigned int* __restrict__ projP) {
  const int lane = threadIdx.x & 63;
  const int w = threadIdx.x >> 6;
  const int wj = w >> 1, wi = w & 1;
  const int jt = blockIdx.y * 128 + wj * 64;   // multiple of 64
  const int it = blockIdx.x * 128 + wi * 64;
  const int c = lane & 15, h = lane >> 4;

  f32x4 acc[4][4];
#pragma unroll
  for (int m = 0; m < 4; m++)
#pragma unroll
    for (int n = 0; n < 4; n++) acc[m][n] = f32x4{0.f, 0.f, 0.f, 0.f};

  const unsigned short* wptr = wb + (size_t)(jt + c) * MD + h * 8;
  const unsigned short* xptr = xb + (size_t)(it + c) * MD + h * 8;

  for (int k0 = 0; k0 < MD; k0 += 32) {
    short8 a[4], bfr[4];
#pragma unroll
    for (int mm = 0; mm < 4; mm++)
      a[mm] = *reinterpret_cast<const short8*>(wptr + mm * 16 * MD + k0);
#pragma unroll
    for (int nn = 0; nn < 4; nn++)
      bfr[nn] = *reinterpret_cast<const short8*>(xptr + nn * 16 * MD + k0);
#pragma unroll
    for (int mm = 0; mm < 4; mm++)
#pragma unroll
      for (int nn = 0; nn < 4; nn++)
        acc[mm][nn] = __builtin_amdgcn_mfma_f32_16x16x32_bf16(a[mm], bfr[nn], acc[mm][nn], 0, 0, 0);
  }

  // epilogue: j = jt + 16*mm + 4*h + r -> n = j>>5 (pair), o = j&31
  const int mglob = jt >> 6;  // n-pair index
#pragma unroll
  for (int mm01 = 0; mm01 < 2; mm01++) {
#pragma unroll
    for (int r = 0; r < 4; r++) {
      const int o = mm01 * 16 + h * 4 + r;
      unsigned int* orow = projP + (size_t)(mglob * 32 + o) * BS + it + c;
#pragma unroll
      for (int nn = 0; nn < 4; nn++) {
        orow[nn * 16] = bc<unsigned int>(
            __builtin_amdgcn_cvt_pkrtz(acc[mm01][nn][r], acc[mm01 + 2][nn][r]));
      }
    }
  }
}

// ---------------- A[o][gi] = f32 row-sum of packed f16 pairs ----------------
// MUST use the same ascending-m pk_add chain as dist's S-chain (diag exactness)
__global__ __launch_bounds__(256) void asum_kernel(const unsigned int* __restrict__ projP,
                                                   float* __restrict__ A) {
  int idx = blockIdx.x * 256 + threadIdx.x;   // 32*8192 total
  int gi = idx & 8191, o = idx >> 13;
  unsigned a2 = 0u;
#pragma unroll
  for (int m = 0; m < 16; m++)
    a2 = pk_add(a2, projP[(size_t)(m * 32 + o) * BS + gi]);
  f16x2 af = bc<f16x2>(a2);
  A[((size_t)o << 13) + gi] = (float)af[0] + (float)af[1];
}

// ---------------- phase 2: distances + exp, all operands from LDS ----------------
// Block = (b, o, ihalf): 256 threads; wave w stages & processes k-quarter
// [64w, 64w+64). Lane t owns rows i = ih*128 + t + 64r (r=0,1), but row data
// is READ FROM LDS per use (quarters 2ih, 2ih+1) -> tiny live register set.
// Sum|a-b| = 2*Smax - A_i - A_k ; out += exp2(fma(S,-2,Ai+Ak)*log2e)
__global__ __launch_bounds__(256, 8) void dist_kernel(const unsigned int* __restrict__ projP,
                                                      const float* __restrict__ A,
                                                      float* __restrict__ out) {
  const int tid = threadIdx.x;
  const int t = tid & 63;   // lane
  const int w = tid >> 6;   // wave = k-quarter
  const int bid = blockIdx.x;                   // 32b * 32o * 2ih
  const int ih = bid & 1, o = (bid >> 1) & 31, b = bid >> 6;
  const int ibase = b * 256;

  __shared__ uint4 kv4[4][16][16];   // [quarter][m][kq] = 16 KB
  __shared__ float A_lds[256];       // 1 KB
  __shared__ float outp[4][128];     // 2 KB

  // stage this wave's k-quarter (coalesced; stride-1 u32 writes)
#pragma unroll
  for (int m = 0; m < 16; m++)
    reinterpret_cast<unsigned*>(&kv4[w][m][0])[t] =
        projP[(size_t)(m * 32 + o) * BS + ibase + w * 64 + t];
  A_lds[tid] = A[((size_t)o << 13) + ibase + tid];
  __syncthreads();

  const float Af0 = A_lds[ih * 128 + t];
  const float Af1 = A_lds[ih * 128 + 64 + t];
  const unsigned* pq0 = reinterpret_cast<const unsigned*>(&kv4[2 * ih][0][0]);
  const unsigned* pq1 = reinterpret_cast<const unsigned*>(&kv4[2 * ih + 1][0][0]);

  float outv0 = 0.f, outv1 = 0.f;
  for (int kq = 0; kq < 16; ++kq) {
    unsigned s0[4] = {0u, 0u, 0u, 0u}, s1[4] = {0u, 0u, 0u, 0u};
    // opaque lane index depending on kq: pins the p-reads inside this loop
    // (prevents hoisting all 32 row-words into registers -> restructuring)
    unsigned tz = t;
    asm("" : "+v"(tz) : "v"(kq));
#pragma unroll
    for (int m = 0; m < 16; m++) {
      const uint4 kw = kv4[w][m][kq];          // wave-uniform broadcast b128
      const unsigned pa = pq0[m * 64 + tz];    // stride-1 u32, 2-way alias = free
      const unsigned pb = pq1[m * 64 + tz];
      s0[0] = pk_add(s0[0], pk_max(pa, kw.x));
      s0[1] = pk_add(s0[1], pk_max(pa, kw.y));
      s0[2] = pk_add(s0[2], pk_max(pa, kw.z));
      s0[3] = pk_add(s0[3], pk_max(pa, kw.w));
      s1[0] = pk_add(s1[0], pk_max(pb, kw.x));
      s1[1] = pk_add(s1[1], pk_max(pb, kw.y));
      s1[2] = pk_add(s1[2], pk_max(pb, kw.z));
      s1[3] = pk_add(s1[3], pk_max(pb, kw.w));
    }
    const f32x4 akq = *reinterpret_cast<const f32x4*>(&A_lds[w * 64 + kq * 4]);
#pragma unroll
    for (int q = 0; q < 4; q++) {
      const float Aq = akq[q];
      const f16x2 v0 = bc<f16x2>(s0[q]);
      const f16x2 v1 = bc<f16x2>(s1[q]);
      const float S0 = (float)v0[0] + (float)v0[1];
      const float S1 = (float)v1[0] + (float)v1[1];
      outv0 += exp2f(fmaf(S0, -2.0f, Af0 + Aq) * 1.4426950408889634f);
      outv1 += exp2f(fmaf(S1, -2.0f, Af1 + Aq) * 1.4426950408889634f);
    }
  }

  // cross-wave reduction over the 4 k-quarters, then direct store
  outp[w][t] = outv0;
  outp[w][64 + t] = outv1;
  __syncthreads();
  if (tid < 128) {
    float v = outp[0][tid] + outp[1][tid] + outp[2][tid] + outp[3][tid];
    out[(size_t)b * 8192 + (size_t)(ih * 128 + tid) * 32 + o] = v;
  }
}

extern "C" void kernel_launch(void* const* d_in, const int* in_sizes, int n_in,
                              void* d_out, int out_size, void* d_ws, size_t ws_size,
                              hipStream_t stream) {
  const float* x = (const float*)d_in[0];   // (32,256,1024) f32
  const float* W = (const float*)d_in[1];   // (1024,1024) f32
  float* out = (float*)d_out;               // (32, 8192) f32

  char* ws = (char*)d_ws;
  unsigned short* xb = (unsigned short*)ws;                          // 16 MB
  unsigned short* wbf = (unsigned short*)(ws + (16u << 20));         //  2 MB
  unsigned int* projP = (unsigned int*)(ws + (18u << 20));           // 16 MB
  float* Abuf = (float*)(ws + (34u << 20));                          //  1 MB

  {
    int n4 = (BS * MD) / 4;  // 2097152
    cast_bf16_kernel<<<(n4 + 255) / 256, 256, 0, stream>>>(x, xb, n4);
  }
  {
    int n4 = (NO * MD) / 4;  // 262144
    cast_bf16_kernel<<<(n4 + 255) / 256, 256, 0, stream>>>(W, wbf, n4);
  }
  {
    dim3 grid(BS / 128, NO / 128);  // (64, 8)
    gemm_kernel<<<grid, 256, 0, stream>>>(xb, wbf, projP);
  }
  asum_kernel<<<(32 * BS) / 256, 256, 0, stream>>>(projP, Abuf);
  dist_kernel<<<32 * 32 * 2, 256, 0, stream>>>(projP, Abuf, out);
}